// Round 2
// baseline (2587.998 us; speedup 1.0000x reference)
//
#include <hip/hip_runtime.h>
#include <cstdint>
#include <cstddef>

#define U4    512   // 4*U
#define UNITS 128
#define BATCH 256
#define TSEQ  512
#define FEAT  64

// ---------------- fast activations (fp32, ~1e-7 rel err) ----------------
__device__ __forceinline__ float sigm(float x) {
    float e = __expf(-x);
    return __fdividef(1.0f, 1.0f + e);
}
__device__ __forceinline__ float tanh_fast(float x) {
    float e = __expf(2.0f * x);
    return 1.0f - __fdividef(2.0f, e + 1.0f);
}

__device__ __forceinline__ float rl(float v, int lane) {
    return __int_as_float(__builtin_amdgcn_readlane(__float_as_int(v), lane));
}

// ---------------- projection GEMM ----------------
// out[M x 512] = in[M x K] @ W[K x 512] + bias   (unchanged from R1)
__global__ __launch_bounds__(256, 4)
void proj_gemm(const float* __restrict__ in, const float* __restrict__ W,
               const float* __restrict__ bias, float* __restrict__ out,
               int K, int sB, int sT, int t0, int tcShift)
{
    const int tid = threadIdx.x;
    const int tx = tid & 31;
    const int ty = tid >> 5;
    const int m0 = blockIdx.x * 64;
    const int n0 = blockIdx.y * 128;
    const int TcMask = (1 << tcShift) - 1;

    __shared__ float As[32][68];
    __shared__ float Bs[32][128];

    float4 acc[8];
    #pragma unroll
    for (int i = 0; i < 8; ++i) acc[i] = make_float4(0.f, 0.f, 0.f, 0.f);

    for (int k0 = 0; k0 < K; k0 += 32) {
        #pragma unroll
        for (int i = 0; i < 8; ++i) {
            int l = i * 256 + tid;
            int row = l >> 5, kk = l & 31;
            int rg = m0 + row;
            int b = rg >> tcShift, tc = rg & TcMask;
            As[kk][row] = in[(size_t)b * sB + (size_t)(t0 + tc) * sT + k0 + kk];
        }
        #pragma unroll
        for (int i = 0; i < 4; ++i) {
            int l = i * 256 + tid;
            int kk = l >> 5, jq = l & 31;
            float4 w4 = *(const float4*)(W + (size_t)(k0 + kk) * U4 + n0 + jq * 4);
            *(float4*)(&Bs[kk][jq * 4]) = w4;
        }
        __syncthreads();
        #pragma unroll
        for (int kk = 0; kk < 32; ++kk) {
            float4 b4 = *(const float4*)(&Bs[kk][tx * 4]);
            float4 a0 = *(const float4*)(&As[kk][ty * 8]);
            float4 a1 = *(const float4*)(&As[kk][ty * 8 + 4]);
            float a[8] = {a0.x, a0.y, a0.z, a0.w, a1.x, a1.y, a1.z, a1.w};
            #pragma unroll
            for (int i = 0; i < 8; ++i) {
                acc[i].x = __builtin_fmaf(a[i], b4.x, acc[i].x);
                acc[i].y = __builtin_fmaf(a[i], b4.y, acc[i].y);
                acc[i].z = __builtin_fmaf(a[i], b4.z, acc[i].z);
                acc[i].w = __builtin_fmaf(a[i], b4.w, acc[i].w);
            }
        }
        __syncthreads();
    }

    float4 bb = *(const float4*)(bias + n0 + tx * 4);
    #pragma unroll
    for (int i = 0; i < 8; ++i) {
        int rg = m0 + ty * 8 + i;
        float4 v = acc[i];
        v.x += bb.x; v.y += bb.y; v.z += bb.z; v.w += bb.w;
        *(float4*)(out + (size_t)rg * U4 + n0 + tx * 4) = v;
    }
}

// ---------------- LSTM recurrence ----------------
// One block per batch row; 512 threads (8 waves), thread j owns gate-column j.
// R column held in VGPRs: 128 floats/thread. amdgpu_waves_per_eu(2,2) pins the
// register budget to 256 VGPR/wave so the allocator keeps R resident instead
// of demoting to scratch (R1 showed VGPR_Count=76 -> R was reloaded per step,
// 2.2x VALU inflation). h broadcast via v_readlane -> SGPR operand on v_fmac.
__global__ __launch_bounds__(512)
__attribute__((amdgpu_waves_per_eu(2, 2)))
void lstm_rec(const float* __restrict__ xw, const float* __restrict__ R,
              float* __restrict__ h_state, float* __restrict__ c_state,
              float* __restrict__ h_out, int Tc, int init)
{
    const int j = threadIdx.x;
    const int b = blockIdx.x;
    const int lane = j & 63;

    __shared__ float lds_h[UNITS];
    __shared__ float lds_z[U4];

    // R column j into registers: Rr[k] = R[k][j]. Coalesced across lanes.
    float Rr[UNITS];
    #pragma unroll
    for (int k = 0; k < UNITS; ++k) Rr[k] = R[(size_t)k * U4 + j];

    float c = 0.f;
    if (j < UNITS) {
        float h0 = 0.f;
        if (!init) {
            h0 = h_state[b * UNITS + j];
            c  = c_state[b * UNITS + j];
        }
        lds_h[j] = h0;
    }
    __syncthreads();

    const float* xwB = xw + (size_t)b * Tc * U4;
    float xwc = xwB[j];

    #pragma unroll 1
    for (int t = 0; t < Tc; ++t) {
        int tn = (t + 1 < Tc) ? (t + 1) : t;
        float xwn = xwB[(size_t)tn * U4 + j];

        // per-wave copy of h: lane k holds h[k] (vh0) and h[64+k] (vh1)
        float vh0 = lds_h[lane];
        float vh1 = lds_h[lane + 64];

        // 4 independent FMA chains: dep latency (~4cyc) fully covered at
        // 2cyc issue with 2+ chains; 4 gives margin.
        float z0 = xwc, z1 = 0.f, z2 = 0.f, z3 = 0.f;
        #pragma unroll
        for (int i = 0; i < 16; ++i) {
            float h0 = rl(vh0, 4 * i + 0);
            float h1 = rl(vh0, 4 * i + 1);
            float h2 = rl(vh0, 4 * i + 2);
            float h3 = rl(vh0, 4 * i + 3);
            z0 = __builtin_fmaf(h0, Rr[4 * i + 0], z0);
            z1 = __builtin_fmaf(h1, Rr[4 * i + 1], z1);
            z2 = __builtin_fmaf(h2, Rr[4 * i + 2], z2);
            z3 = __builtin_fmaf(h3, Rr[4 * i + 3], z3);
        }
        #pragma unroll
        for (int i = 0; i < 16; ++i) {
            float h0 = rl(vh1, 4 * i + 0);
            float h1 = rl(vh1, 4 * i + 1);
            float h2 = rl(vh1, 4 * i + 2);
            float h3 = rl(vh1, 4 * i + 3);
            z0 = __builtin_fmaf(h0, Rr[64 + 4 * i + 0], z0);
            z1 = __builtin_fmaf(h1, Rr[64 + 4 * i + 1], z1);
            z2 = __builtin_fmaf(h2, Rr[64 + 4 * i + 2], z2);
            z3 = __builtin_fmaf(h3, Rr[64 + 4 * i + 3], z3);
        }
        float zj = (z0 + z1) + (z2 + z3);

        // wave-uniform gate classes: waves 0-3 sigm(i,f), 4-5 tanh(g), 6-7 sigm(o)
        float a;
        if (j < 256)      a = sigm(zj);
        else if (j < 384) a = tanh_fast(zj);
        else              a = sigm(zj);
        lds_z[j] = a;
        __syncthreads();

        if (j < UNITS) {
            float iv = lds_z[j];
            float fv = lds_z[j + 128];
            float gv = lds_z[j + 256];
            float ov = lds_z[j + 384];
            c = __builtin_fmaf(fv, c, iv * gv);
            float hv = ov * tanh_fast(c);
            lds_h[j] = hv;
            if (h_out) h_out[((size_t)b * Tc + t) * UNITS + j] = hv;
        }
        __syncthreads();
        xwc = xwn;
    }

    if (j < UNITS) {
        h_state[b * UNITS + j] = lds_h[j];
        c_state[b * UNITS + j] = c;
    }
}

// ---------------- dense head ----------------
__global__ __launch_bounds__(256)
void dense_head(const float* __restrict__ h2, const float* __restrict__ Wd,
                const float* __restrict__ bd, float* __restrict__ out)
{
    int b = threadIdx.x;
    float acc[6];
    #pragma unroll
    for (int o = 0; o < 6; ++o) acc[o] = bd[o];
    #pragma unroll 4
    for (int k = 0; k < UNITS; ++k) {
        float hv = h2[b * UNITS + k];
        #pragma unroll
        for (int o = 0; o < 6; ++o)
            acc[o] = __builtin_fmaf(hv, Wd[k * 6 + o], acc[o]);
    }
    #pragma unroll
    for (int o = 0; o < 6; ++o) out[b * 6 + o] = acc[o];
}

extern "C" void kernel_launch(void* const* d_in, const int* in_sizes, int n_in,
                              void* d_out, int out_size, void* d_ws, size_t ws_size,
                              hipStream_t stream)
{
    (void)in_sizes; (void)n_in; (void)out_size;
    const float* x  = (const float*)d_in[0];
    const float* Ws[3] = {(const float*)d_in[1], (const float*)d_in[4], (const float*)d_in[7]};
    const float* Rs[3] = {(const float*)d_in[2], (const float*)d_in[5], (const float*)d_in[8]};
    const float* bs[3] = {(const float*)d_in[3], (const float*)d_in[6], (const float*)d_in[9]};
    const float* Wd = (const float*)d_in[10];
    const float* bd = (const float*)d_in[11];
    float* out = (float*)d_out;

    int tcShift = 7;
    while (tcShift > 2) {
        size_t need = ((size_t)1 << tcShift) * 655360u + 786432u;
        if (need <= ws_size) break;
        --tcShift;
    }
    const int Tc = 1 << tcShift;

    float* xw = (float*)d_ws;                                // [B][Tc][512]
    float* hc = xw + (size_t)BATCH * Tc * U4;                // [B][Tc][128]
    float* hs = hc + (size_t)BATCH * Tc * UNITS;             // 3 x [B][128]
    float* cs = hs + 3 * BATCH * UNITS;                      // 3 x [B][128]

    const int nChunks = TSEQ / Tc;
    for (int ch = 0; ch < nChunks; ++ch) {
        const int t0 = ch * Tc;
        for (int layer = 0; layer < 3; ++layer) {
            const float* in = (layer == 0) ? x : hc;
            const int K  = (layer == 0) ? FEAT : UNITS;
            const int sB = (layer == 0) ? TSEQ * FEAT : Tc * UNITS;
            const int sT = K;
            const int pt0 = (layer == 0) ? t0 : 0;

            dim3 grid(BATCH * Tc / 64, 4);
            proj_gemm<<<grid, 256, 0, stream>>>(in, Ws[layer], bs[layer], xw,
                                                K, sB, sT, pt0, tcShift);

            float* hOut = (layer < 2) ? hc : nullptr;
            lstm_rec<<<BATCH, 512, 0, stream>>>(xw, Rs[layer],
                                                hs + layer * BATCH * UNITS,
                                                cs + layer * BATCH * UNITS,
                                                hOut, Tc, (ch == 0) ? 1 : 0);
        }
    }
    dense_head<<<1, 256, 0, stream>>>(hs + 2 * BATCH * UNITS, Wd, bd, out);
}

// Round 3
// 2563.767 us; speedup vs baseline: 1.0095x; 1.0095x over previous
//
#include <hip/hip_runtime.h>
#include <cstdint>
#include <cstddef>

#define U4    512   // 4*U
#define UNITS 128
#define BATCH 256
#define TSEQ  512
#define FEAT  64

typedef float f4 __attribute__((ext_vector_type(4)));

// ---------------- fast activations (fp32, ~1e-7 rel err) ----------------
__device__ __forceinline__ float sigm(float x) {
    float e = __expf(-x);
    return __fdividef(1.0f, 1.0f + e);
}
__device__ __forceinline__ float tanh_fast(float x) {
    float e = __expf(2.0f * x);
    return 1.0f - __fdividef(2.0f, e + 1.0f);
}
__device__ __forceinline__ float rl(float v, int lane) {
    return __int_as_float(__builtin_amdgcn_readlane(__float_as_int(v), lane));
}

// ---------------- projection GEMM (unchanged from R1) ----------------
__global__ __launch_bounds__(256, 4)
void proj_gemm(const float* __restrict__ in, const float* __restrict__ W,
               const float* __restrict__ bias, float* __restrict__ out,
               int K, int sB, int sT, int t0, int tcShift)
{
    const int tid = threadIdx.x;
    const int tx = tid & 31;
    const int ty = tid >> 5;
    const int m0 = blockIdx.x * 64;
    const int n0 = blockIdx.y * 128;
    const int TcMask = (1 << tcShift) - 1;

    __shared__ float As[32][68];
    __shared__ float Bs[32][128];

    float4 acc[8];
    #pragma unroll
    for (int i = 0; i < 8; ++i) acc[i] = make_float4(0.f, 0.f, 0.f, 0.f);

    for (int k0 = 0; k0 < K; k0 += 32) {
        #pragma unroll
        for (int i = 0; i < 8; ++i) {
            int l = i * 256 + tid;
            int row = l >> 5, kk = l & 31;
            int rg = m0 + row;
            int b = rg >> tcShift, tc = rg & TcMask;
            As[kk][row] = in[(size_t)b * sB + (size_t)(t0 + tc) * sT + k0 + kk];
        }
        #pragma unroll
        for (int i = 0; i < 4; ++i) {
            int l = i * 256 + tid;
            int kk = l >> 5, jq = l & 31;
            float4 w4 = *(const float4*)(W + (size_t)(k0 + kk) * U4 + n0 + jq * 4);
            *(float4*)(&Bs[kk][jq * 4]) = w4;
        }
        __syncthreads();
        #pragma unroll
        for (int kk = 0; kk < 32; ++kk) {
            float4 b4 = *(const float4*)(&Bs[kk][tx * 4]);
            float4 a0 = *(const float4*)(&As[kk][ty * 8]);
            float4 a1 = *(const float4*)(&As[kk][ty * 8 + 4]);
            float a[8] = {a0.x, a0.y, a0.z, a0.w, a1.x, a1.y, a1.z, a1.w};
            #pragma unroll
            for (int i = 0; i < 8; ++i) {
                acc[i].x = __builtin_fmaf(a[i], b4.x, acc[i].x);
                acc[i].y = __builtin_fmaf(a[i], b4.y, acc[i].y);
                acc[i].z = __builtin_fmaf(a[i], b4.z, acc[i].z);
                acc[i].w = __builtin_fmaf(a[i], b4.w, acc[i].w);
            }
        }
        __syncthreads();
    }

    float4 bb = *(const float4*)(bias + n0 + tx * 4);
    #pragma unroll
    for (int i = 0; i < 8; ++i) {
        int rg = m0 + ty * 8 + i;
        float4 v = acc[i];
        v.x += bb.x; v.y += bb.y; v.z += bb.z; v.w += bb.w;
        *(float4*)(out + (size_t)rg * U4 + n0 + tx * 4) = v;
    }
}

// ---------------- LSTM recurrence ----------------
// One block per batch row; 512 threads (8 waves), thread j owns gate-column j.
// R column pinned in VGPRs behind opaque asm defs: the allocator re-loaded
// loop-invariant global loads from L2 every step in R1/R2 (VGPR_Count 76/88,
// ~30 TB/s implied L2 traffic = the bottleneck). asm results cannot be
// rematerialized, so with the 256-VGPR budget (__launch_bounds__(512,2))
// the values must stay resident.
#define LOADQ(i)                                                     \
    f4 qA##i; qA##i.x = Rc[(4*i+0)*U4]; qA##i.y = Rc[(4*i+1)*U4];    \
              qA##i.z = Rc[(4*i+2)*U4]; qA##i.w = Rc[(4*i+3)*U4];    \
    asm("" : "+v"(qA##i));                                           \
    f4 qB##i; qB##i.x = Rc[(64+4*i+0)*U4]; qB##i.y = Rc[(64+4*i+1)*U4]; \
              qB##i.z = Rc[(64+4*i+2)*U4]; qB##i.w = Rc[(64+4*i+3)*U4]; \
    asm("" : "+v"(qB##i));

#define FMAQ(i)                                                \
    z0 = __builtin_fmaf(rl(vh0, 4*i+0), qA##i.x, z0);          \
    z1 = __builtin_fmaf(rl(vh1, 4*i+0), qB##i.x, z1);          \
    z0 = __builtin_fmaf(rl(vh0, 4*i+1), qA##i.y, z0);          \
    z1 = __builtin_fmaf(rl(vh1, 4*i+1), qB##i.y, z1);          \
    z0 = __builtin_fmaf(rl(vh0, 4*i+2), qA##i.z, z0);          \
    z1 = __builtin_fmaf(rl(vh1, 4*i+2), qB##i.z, z1);          \
    z0 = __builtin_fmaf(rl(vh0, 4*i+3), qA##i.w, z0);          \
    z1 = __builtin_fmaf(rl(vh1, 4*i+3), qB##i.w, z1);

__global__ __launch_bounds__(512, 2)
void lstm_rec(const float* __restrict__ xw, const float* __restrict__ R,
              float* __restrict__ h_state, float* __restrict__ c_state,
              float* __restrict__ h_out, int Tc, int init)
{
    const int j = threadIdx.x;
    const int b = blockIdx.x;
    const int lane = j & 63;

    __shared__ float lds_h[UNITS];
    __shared__ float lds_z[U4];

    const float* Rc = R + j;   // column j, rows stride U4
    LOADQ(0)  LOADQ(1)  LOADQ(2)  LOADQ(3)
    LOADQ(4)  LOADQ(5)  LOADQ(6)  LOADQ(7)
    LOADQ(8)  LOADQ(9)  LOADQ(10) LOADQ(11)
    LOADQ(12) LOADQ(13) LOADQ(14) LOADQ(15)

    float c = 0.f;
    if (j < UNITS) {
        float h0 = 0.f;
        if (!init) {
            h0 = h_state[b * UNITS + j];
            c  = c_state[b * UNITS + j];
        }
        lds_h[j] = h0;
    }
    __syncthreads();

    const float* xwB = xw + (size_t)b * Tc * U4;
    float xwc = xwB[j];

    #pragma unroll 1
    for (int t = 0; t < Tc; ++t) {
        int tn = (t + 1 < Tc) ? (t + 1) : t;
        float xwn = xwB[(size_t)tn * U4 + j];

        // per-wave copy of h: lane k holds h[k] (vh0) and h[64+k] (vh1)
        float vh0 = lds_h[lane];
        float vh1 = lds_h[lane + 64];

        float z0 = xwc, z1 = 0.f;   // two chains: k=0..63 and k=64..127
        FMAQ(0)  FMAQ(1)  FMAQ(2)  FMAQ(3)
        FMAQ(4)  FMAQ(5)  FMAQ(6)  FMAQ(7)
        FMAQ(8)  FMAQ(9)  FMAQ(10) FMAQ(11)
        FMAQ(12) FMAQ(13) FMAQ(14) FMAQ(15)
        float zj = z0 + z1;

        // wave-uniform gate classes: waves 0-3 sigm(i,f), 4-5 tanh(g), 6-7 sigm(o)
        float a;
        if (j < 256)      a = sigm(zj);
        else if (j < 384) a = tanh_fast(zj);
        else              a = sigm(zj);
        lds_z[j] = a;
        __syncthreads();

        if (j < UNITS) {
            float iv = lds_z[j];
            float fv = lds_z[j + 128];
            float gv = lds_z[j + 256];
            float ov = lds_z[j + 384];
            c = __builtin_fmaf(fv, c, iv * gv);
            float hv = ov * tanh_fast(c);
            lds_h[j] = hv;
            if (h_out) h_out[((size_t)b * Tc + t) * UNITS + j] = hv;
        }
        __syncthreads();
        xwc = xwn;
    }

    if (j < UNITS) {
        h_state[b * UNITS + j] = lds_h[j];
        c_state[b * UNITS + j] = c;
    }
}

// ---------------- dense head ----------------
__global__ __launch_bounds__(256)
void dense_head(const float* __restrict__ h2, const float* __restrict__ Wd,
                const float* __restrict__ bd, float* __restrict__ out)
{
    int b = threadIdx.x;
    float acc[6];
    #pragma unroll
    for (int o = 0; o < 6; ++o) acc[o] = bd[o];
    #pragma unroll 4
    for (int k = 0; k < UNITS; ++k) {
        float hv = h2[b * UNITS + k];
        #pragma unroll
        for (int o = 0; o < 6; ++o)
            acc[o] = __builtin_fmaf(hv, Wd[k * 6 + o], acc[o]);
    }
    #pragma unroll
    for (int o = 0; o < 6; ++o) out[b * 6 + o] = acc[o];
}

extern "C" void kernel_launch(void* const* d_in, const int* in_sizes, int n_in,
                              void* d_out, int out_size, void* d_ws, size_t ws_size,
                              hipStream_t stream)
{
    (void)in_sizes; (void)n_in; (void)out_size;
    const float* x  = (const float*)d_in[0];
    const float* Ws[3] = {(const float*)d_in[1], (const float*)d_in[4], (const float*)d_in[7]};
    const float* Rs[3] = {(const float*)d_in[2], (const float*)d_in[5], (const float*)d_in[8]};
    const float* bs[3] = {(const float*)d_in[3], (const float*)d_in[6], (const float*)d_in[9]};
    const float* Wd = (const float*)d_in[10];
    const float* bd = (const float*)d_in[11];
    float* out = (float*)d_out;

    int tcShift = 7;
    while (tcShift > 2) {
        size_t need = ((size_t)1 << tcShift) * 655360u + 786432u;
        if (need <= ws_size) break;
        --tcShift;
    }
    const int Tc = 1 << tcShift;

    float* xw = (float*)d_ws;                                // [B][Tc][512]
    float* hc = xw + (size_t)BATCH * Tc * U4;                // [B][Tc][128]
    float* hs = hc + (size_t)BATCH * Tc * UNITS;             // 3 x [B][128]
    float* cs = hs + 3 * BATCH * UNITS;                      // 3 x [B][128]

    const int nChunks = TSEQ / Tc;
    for (int ch = 0; ch < nChunks; ++ch) {
        const int t0 = ch * Tc;
        for (int layer = 0; layer < 3; ++layer) {
            const float* in = (layer == 0) ? x : hc;
            const int K  = (layer == 0) ? FEAT : UNITS;
            const int sB = (layer == 0) ? TSEQ * FEAT : Tc * UNITS;
            const int sT = K;
            const int pt0 = (layer == 0) ? t0 : 0;

            dim3 grid(BATCH * Tc / 64, 4);
            proj_gemm<<<grid, 256, 0, stream>>>(in, Ws[layer], bs[layer], xw,
                                                K, sB, sT, pt0, tcShift);

            float* hOut = (layer < 2) ? hc : nullptr;
            lstm_rec<<<BATCH, 512, 0, stream>>>(xw, Rs[layer],
                                                hs + layer * BATCH * UNITS,
                                                cs + layer * BATCH * UNITS,
                                                hOut, Tc, (ch == 0) ? 1 : 0);
        }
    }
    dense_head<<<1, 256, 0, stream>>>(hs + 2 * BATCH * UNITS, Wd, bd, out);
}

// Round 4
// 2417.847 us; speedup vs baseline: 1.0704x; 1.0604x over previous
//
#include <hip/hip_runtime.h>
#include <cstdint>
#include <cstddef>

#define U4    512   // 4*U
#define UNITS 128
#define BATCH 256
#define TSEQ  512
#define FEAT  64

typedef float f4 __attribute__((ext_vector_type(4)));

// ---------------- fast activations (fp32, ~1e-7 rel err) ----------------
__device__ __forceinline__ float sigm(float x) {
    float e = __expf(-x);
    return __fdividef(1.0f, 1.0f + e);
}
__device__ __forceinline__ float tanh_fast(float x) {
    float e = __expf(2.0f * x);
    return 1.0f - __fdividef(2.0f, e + 1.0f);
}
__device__ __forceinline__ float rl(float v, int lane) {
    return __int_as_float(__builtin_amdgcn_readlane(__float_as_int(v), lane));
}

// ---------------- projection GEMM (unchanged from R1) ----------------
__global__ __launch_bounds__(256, 4)
void proj_gemm(const float* __restrict__ in, const float* __restrict__ W,
               const float* __restrict__ bias, float* __restrict__ out,
               int K, int sB, int sT, int t0, int tcShift)
{
    const int tid = threadIdx.x;
    const int tx = tid & 31;
    const int ty = tid >> 5;
    const int m0 = blockIdx.x * 64;
    const int n0 = blockIdx.y * 128;
    const int TcMask = (1 << tcShift) - 1;

    __shared__ float As[32][68];
    __shared__ float Bs[32][128];

    float4 acc[8];
    #pragma unroll
    for (int i = 0; i < 8; ++i) acc[i] = make_float4(0.f, 0.f, 0.f, 0.f);

    for (int k0 = 0; k0 < K; k0 += 32) {
        #pragma unroll
        for (int i = 0; i < 8; ++i) {
            int l = i * 256 + tid;
            int row = l >> 5, kk = l & 31;
            int rg = m0 + row;
            int b = rg >> tcShift, tc = rg & TcMask;
            As[kk][row] = in[(size_t)b * sB + (size_t)(t0 + tc) * sT + k0 + kk];
        }
        #pragma unroll
        for (int i = 0; i < 4; ++i) {
            int l = i * 256 + tid;
            int kk = l >> 5, jq = l & 31;
            float4 w4 = *(const float4*)(W + (size_t)(k0 + kk) * U4 + n0 + jq * 4);
            *(float4*)(&Bs[kk][jq * 4]) = w4;
        }
        __syncthreads();
        #pragma unroll
        for (int kk = 0; kk < 32; ++kk) {
            float4 b4 = *(const float4*)(&Bs[kk][tx * 4]);
            float4 a0 = *(const float4*)(&As[kk][ty * 8]);
            float4 a1 = *(const float4*)(&As[kk][ty * 8 + 4]);
            float a[8] = {a0.x, a0.y, a0.z, a0.w, a1.x, a1.y, a1.z, a1.w};
            #pragma unroll
            for (int i = 0; i < 8; ++i) {
                acc[i].x = __builtin_fmaf(a[i], b4.x, acc[i].x);
                acc[i].y = __builtin_fmaf(a[i], b4.y, acc[i].y);
                acc[i].z = __builtin_fmaf(a[i], b4.z, acc[i].z);
                acc[i].w = __builtin_fmaf(a[i], b4.w, acc[i].w);
            }
        }
        __syncthreads();
    }

    float4 bb = *(const float4*)(bias + n0 + tx * 4);
    #pragma unroll
    for (int i = 0; i < 8; ++i) {
        int rg = m0 + ty * 8 + i;
        float4 v = acc[i];
        v.x += bb.x; v.y += bb.y; v.z += bb.z; v.w += bb.w;
        *(float4*)(out + (size_t)rg * U4 + n0 + tx * 4) = v;
    }
}

// ---------------- LSTM recurrence ----------------
// 1024 threads/block, 1 block/seq. Thread tid owns HALF a gate-column:
//   col = tid & 511, half = tid >> 9 (k-range half*64 .. half*64+63).
// Per-thread live R state = 64 floats -> demand (~90 VGPR) is comfortably
// under the 128-VGPR cap (__launch_bounds__(1024,4)), so the allocator has
// no reason to spill/reload (R1-R3 failure mode: 128 live floats/thread at
// 512 threads never got arch-VGPR residency; 3.2k cyc/step vs 1k floor).
// h broadcast via v_readlane (wave w's threads share one half -> one LDS
// read/wave/step), halves combined through LDS, 3 barriers/step.
#define LOADQ(i)                                                        \
    f4 q##i; q##i.x = Rc[(4*i+0)*U4]; q##i.y = Rc[(4*i+1)*U4];          \
             q##i.z = Rc[(4*i+2)*U4]; q##i.w = Rc[(4*i+3)*U4];          \
    asm("" : "+v"(q##i));

#define FMAQ(i)                                         \
    z0 = __builtin_fmaf(rl(vh, 4*i+0), q##i.x, z0);     \
    z1 = __builtin_fmaf(rl(vh, 4*i+1), q##i.y, z1);     \
    z0 = __builtin_fmaf(rl(vh, 4*i+2), q##i.z, z0);     \
    z1 = __builtin_fmaf(rl(vh, 4*i+3), q##i.w, z1);

__global__ __launch_bounds__(1024, 4)
void lstm_rec(const float* __restrict__ xw, const float* __restrict__ R,
              float* __restrict__ h_state, float* __restrict__ c_state,
              float* __restrict__ h_out, int Tc, int init)
{
    const int tid  = threadIdx.x;
    const int col  = tid & 511;
    const int half = tid >> 9;        // 0: k=0..63, 1: k=64..127
    const int b    = blockIdx.x;
    const int lane = tid & 63;

    __shared__ float lds_zp[1024];    // partial dots
    __shared__ float lds_z[U4];       // activated gates
    __shared__ float lds_h[UNITS];

    // R rows [half*64, half*64+64) of column `col`
    const float* Rc = R + (size_t)(half * 64) * U4 + col;
    LOADQ(0)  LOADQ(1)  LOADQ(2)  LOADQ(3)
    LOADQ(4)  LOADQ(5)  LOADQ(6)  LOADQ(7)
    LOADQ(8)  LOADQ(9)  LOADQ(10) LOADQ(11)
    LOADQ(12) LOADQ(13) LOADQ(14) LOADQ(15)

    float c = 0.f;
    if (tid < UNITS) {
        float h0 = 0.f;
        if (!init) {
            h0 = h_state[b * UNITS + tid];
            c  = c_state[b * UNITS + tid];
        }
        lds_h[tid] = h0;
    }
    __syncthreads();

    const float* xwB = xw + (size_t)b * Tc * U4;
    float xwc = (tid < 512) ? xwB[tid] : 0.f;

    #pragma unroll 1
    for (int t = 0; t < Tc; ++t) {
        int tn = (t + 1 < Tc) ? (t + 1) : t;
        float xwn = (tid < 512) ? xwB[(size_t)tn * U4 + tid] : 0.f;

        // wave-local h fragment: lane L holds h[half*64 + L]
        float vh = lds_h[(half << 6) | lane];

        float z0 = xwc, z1 = 0.f;     // xwc == 0 for half 1
        FMAQ(0)  FMAQ(1)  FMAQ(2)  FMAQ(3)
        FMAQ(4)  FMAQ(5)  FMAQ(6)  FMAQ(7)
        FMAQ(8)  FMAQ(9)  FMAQ(10) FMAQ(11)
        FMAQ(12) FMAQ(13) FMAQ(14) FMAQ(15)
        lds_zp[tid] = z0 + z1;
        __syncthreads();

        // combine halves + activation, spread over 8 waves (1 transcendental
        // pair per thread; gate class is wave-uniform)
        if (tid < 512) {
            float zj = lds_zp[tid] + lds_zp[tid + 512];
            float a;
            if (tid < 256)      a = sigm(zj);       // i, f
            else if (tid < 384) a = tanh_fast(zj);  // g
            else                a = sigm(zj);       // o
            lds_z[tid] = a;
        }
        __syncthreads();

        if (tid < UNITS) {
            float iv = lds_z[tid];
            float fv = lds_z[tid + 128];
            float gv = lds_z[tid + 256];
            float ov = lds_z[tid + 384];
            c = __builtin_fmaf(fv, c, iv * gv);
            float hv = ov * tanh_fast(c);
            lds_h[tid] = hv;
            if (h_out) h_out[((size_t)b * Tc + t) * UNITS + tid] = hv;
        }
        __syncthreads();
        xwc = xwn;
    }

    if (tid < UNITS) {
        h_state[b * UNITS + tid] = lds_h[tid];
        c_state[b * UNITS + tid] = c;
    }
}

// ---------------- dense head ----------------
__global__ __launch_bounds__(256)
void dense_head(const float* __restrict__ h2, const float* __restrict__ Wd,
                const float* __restrict__ bd, float* __restrict__ out)
{
    int b = threadIdx.x;
    float acc[6];
    #pragma unroll
    for (int o = 0; o < 6; ++o) acc[o] = bd[o];
    #pragma unroll 4
    for (int k = 0; k < UNITS; ++k) {
        float hv = h2[b * UNITS + k];
        #pragma unroll
        for (int o = 0; o < 6; ++o)
            acc[o] = __builtin_fmaf(hv, Wd[k * 6 + o], acc[o]);
    }
    #pragma unroll
    for (int o = 0; o < 6; ++o) out[b * 6 + o] = acc[o];
}

extern "C" void kernel_launch(void* const* d_in, const int* in_sizes, int n_in,
                              void* d_out, int out_size, void* d_ws, size_t ws_size,
                              hipStream_t stream)
{
    (void)in_sizes; (void)n_in; (void)out_size;
    const float* x  = (const float*)d_in[0];
    const float* Ws[3] = {(const float*)d_in[1], (const float*)d_in[4], (const float*)d_in[7]};
    const float* Rs[3] = {(const float*)d_in[2], (const float*)d_in[5], (const float*)d_in[8]};
    const float* bs[3] = {(const float*)d_in[3], (const float*)d_in[6], (const float*)d_in[9]};
    const float* Wd = (const float*)d_in[10];
    const float* bd = (const float*)d_in[11];
    float* out = (float*)d_out;

    int tcShift = 7;
    while (tcShift > 2) {
        size_t need = ((size_t)1 << tcShift) * 655360u + 786432u;
        if (need <= ws_size) break;
        --tcShift;
    }
    const int Tc = 1 << tcShift;

    float* xw = (float*)d_ws;                                // [B][Tc][512]
    float* hc = xw + (size_t)BATCH * Tc * U4;                // [B][Tc][128]
    float* hs = hc + (size_t)BATCH * Tc * UNITS;             // 3 x [B][128]
    float* cs = hs + 3 * BATCH * UNITS;                      // 3 x [B][128]

    const int nChunks = TSEQ / Tc;
    for (int ch = 0; ch < nChunks; ++ch) {
        const int t0 = ch * Tc;
        for (int layer = 0; layer < 3; ++layer) {
            const float* in = (layer == 0) ? x : hc;
            const int K  = (layer == 0) ? FEAT : UNITS;
            const int sB = (layer == 0) ? TSEQ * FEAT : Tc * UNITS;
            const int sT = K;
            const int pt0 = (layer == 0) ? t0 : 0;

            dim3 grid(BATCH * Tc / 64, 4);
            proj_gemm<<<grid, 256, 0, stream>>>(in, Ws[layer], bs[layer], xw,
                                                K, sB, sT, pt0, tcShift);

            float* hOut = (layer < 2) ? hc : nullptr;
            lstm_rec<<<BATCH, 1024, 0, stream>>>(xw, Rs[layer],
                                                 hs + layer * BATCH * UNITS,
                                                 cs + layer * BATCH * UNITS,
                                                 hOut, Tc, (ch == 0) ? 1 : 0);
        }
    }
    dense_head<<<1, 256, 0, stream>>>(hs + 2 * BATCH * UNITS, Wd, bd, out);
}